// Round 1
// baseline (332.693 us; speedup 1.0000x reference)
//
#include <hip/hip_runtime.h>

typedef __attribute__((ext_vector_type(8))) short bf16x8;
typedef __attribute__((ext_vector_type(4))) float f32x4;
typedef __attribute__((ext_vector_type(4))) unsigned int u32x4;
typedef __attribute__((ext_vector_type(2))) unsigned int u32x2;

#define NTOK 4096
#define CHD 256
// (1/sqrt(256)) * log2(e) folded into wq/bq so softmax uses exp2 directly
#define QSCALE 0.09016844005556022f

__device__ __forceinline__ unsigned short f2bf(float x) {
    unsigned int u = __builtin_bit_cast(unsigned int, x);
    return (unsigned short)((u + 0x7FFFu + ((u >> 16) & 1u)) >> 16);
}
__device__ __forceinline__ float bf2f(unsigned short u) {
    return __builtin_bit_cast(float, (unsigned int)u << 16);
}
__device__ __forceinline__ f32x4 mfma16(bf16x8 a, bf16x8 b, f32x4 c) {
    return __builtin_amdgcn_mfma_f32_16x16x32_bf16(a, b, c, 0, 0, 0);
}

// ---------------- kernel 1: weights fp32 -> bf16 (wq scaled) ----------------
__global__ __launch_bounds__(256) void wconv_kernel(
    const float* __restrict__ wq, const float* __restrict__ wk,
    const float* __restrict__ wv, unsigned short* __restrict__ wbf)
{
    int idx = blockIdx.x * 256 + threadIdx.x;     // 3*65536 total
    int z = idx >> 16;
    const float* src = (z == 0) ? wq : (z == 1) ? wk : wv;
    float s = (z == 0) ? QSCALE : 1.0f;
    wbf[idx] = f2bf(src[idx & 65535] * s);
}

// ---------------- kernel 2: fused 1x1-conv projection -----------------------
// out[n][d] = sum_c x[c][n]*w[d][c] + bias[d]
// z=0 -> Q (B,N,C) scaled; z=1 -> K (B,N,C); z=2 -> V^T (B,C,N)
__global__ __launch_bounds__(256) void proj_kernel(
    const float* __restrict__ xq, const float* __restrict__ xk, const float* __restrict__ xv,
    const float* __restrict__ bq, const float* __restrict__ bk, const float* __restrict__ bv,
    const unsigned short* __restrict__ wbf,
    unsigned short* __restrict__ Qo, unsigned short* __restrict__ Ko,
    unsigned short* __restrict__ VTo)
{
    __shared__ __align__(16) unsigned short alds[64 * 264];   // 64 tokens x 256 c, pitch 264
    __shared__ __align__(16) unsigned char wlds[16384];       // 32 d x 256 c bf16, swizzled
    const int z = blockIdx.y;
    const int b = blockIdx.x >> 6;
    const int n0 = (blockIdx.x & 63) << 6;
    const float* x    = (z == 0) ? xq : (z == 1) ? xk : xv;
    const float* bias = (z == 0) ? bq : (z == 1) ? bk : bv;
    const unsigned short* w = wbf + z * 65536;
    const int t = threadIdx.x;
    const int wv_ = t >> 6, l = t & 63, lr = l & 15, lg = l >> 4;

    // stage x tile transposed: (token, c) bf16
    #pragma unroll
    for (int it = 0; it < 16; ++it) {
        int idx = it * 256 + t;
        int c = idx >> 4, j4 = idx & 15;
        f32x4 v = *(const f32x4*)(x + (size_t)(b * CHD + c) * NTOK + n0 + j4 * 4);
        #pragma unroll
        for (int i = 0; i < 4; ++i)
            alds[(j4 * 4 + i) * 264 + c] = f2bf(v[i]);
    }
    __syncthreads();

    // A-frags: wave wv_ owns token rows [wv_*16, +16)
    bf16x8 af[8];
    #pragma unroll
    for (int kk = 0; kk < 8; ++kk)
        af[kk] = *(const bf16x8*)&alds[(wv_ * 16 + lr) * 264 + kk * 32 + lg * 8];

    const float bsc = (z == 0) ? QSCALE : 1.0f;

    for (int dg = 0; dg < 8; ++dg) {
        __syncthreads();
        // stage W rows [dg*32, +32)
        #pragma unroll
        for (int it = 0; it < 4; ++it) {
            int idx = it * 256 + t;                 // 1024 chunks of 16B
            int dr = idx >> 5, c16 = idx & 31;
            u32x4 vv = *(const u32x4*)(w + (size_t)(dg * 32 + dr) * CHD + c16 * 8);
            *(u32x4*)(wlds + ((dr * 512 + c16 * 16) ^ ((dr & 7) << 4))) = vv;
        }
        __syncthreads();
        #pragma unroll
        for (int dbi = 0; dbi < 2; ++dbi) {
            int dr = dbi * 16 + lr;
            int d = dg * 32 + dr;
            float bias_v = bias[d] * bsc;
            f32x4 acc = {bias_v, bias_v, bias_v, bias_v};
            #pragma unroll
            for (int kk = 0; kk < 8; ++kk) {
                bf16x8 bf = *(const bf16x8*)(wlds + ((dr * 512 + kk * 64 + lg * 16) ^ ((dr & 7) << 4)));
                acc = mfma16(af[kk], bf, acc);
            }
            if (z < 2) {
                unsigned short* o = (z == 0) ? Qo : Ko;
                #pragma unroll
                for (int r = 0; r < 4; ++r) {
                    int n = n0 + wv_ * 16 + lg * 4 + r;
                    o[(size_t)(b * NTOK + n) * CHD + d] = f2bf(acc[r]);
                }
            } else {
                int n = n0 + wv_ * 16 + lg * 4;
                u32x2 pk;
                pk[0] = (unsigned)f2bf(acc[0]) | ((unsigned)f2bf(acc[1]) << 16);
                pk[1] = (unsigned)f2bf(acc[2]) | ((unsigned)f2bf(acc[3]) << 16);
                *(u32x2*)(VTo + (size_t)(b * CHD + d) * NTOK + n) = pk;
            }
        }
    }
}

// ---------------- kernel 3: flash attention (KV-split x2) -------------------
// grid 256: xcd=bid&7 -> batch=xcd>>1, half=xcd&1, qtile=bid>>3 (128 q-rows)
__global__ __launch_bounds__(256, 1) void attn_kernel(
    const unsigned short* __restrict__ Qp,   // (B,N,C) pre-scaled
    const unsigned short* __restrict__ Kp,   // (B,N,C)
    const unsigned short* __restrict__ VTp,  // (B,C,N)
    unsigned short* __restrict__ Opart,      // (B,2,C,N) unnormalized bf16
    float* __restrict__ Mpart, float* __restrict__ Lpart)  // (B,2,N)
{
    // [0,32768): K tile, 64 rows x 512B, swz ^((m&7)<<4); P scratch overlays it
    // [32768,65536): V^T tile, 256 rows x 128B, swz ^((d&7)<<4)
    __shared__ __align__(16) unsigned char smem[65536];
    const int bid = blockIdx.x;
    const int xcd = bid & 7;
    const int b = xcd >> 1;
    const int hf = xcd & 1;
    const int n0 = (bid >> 3) * 128;
    const int kvbase = hf * 2048;
    const int t = threadIdx.x;
    const int wv_ = t >> 6, l = t & 63, lr = l & 15, lg = l >> 4;

    const unsigned short* Qb = Qp + (size_t)b * NTOK * CHD;
    const unsigned short* Kb = Kp + (size_t)b * NTOK * CHD;
    const unsigned short* Vb = VTp + (size_t)b * CHD * NTOK;

    // Q fragments in registers: wave owns rows [n0+wv_*32, +32)
    bf16x8 qf[2][8];
    #pragma unroll
    for (int nb = 0; nb < 2; ++nb)
        #pragma unroll
        for (int kk = 0; kk < 8; ++kk)
            qf[nb][kk] = *(const bf16x8*)(Qb + (size_t)(n0 + wv_ * 32 + nb * 16 + lr) * CHD + kk * 32 + lg * 8);

    f32x4 o[2][16];
    #pragma unroll
    for (int nb = 0; nb < 2; ++nb)
        #pragma unroll
        for (int db = 0; db < 16; ++db)
            o[nb][db] = (f32x4){0.f, 0.f, 0.f, 0.f};
    f32x4 mrow[2], lrow[2];
    #pragma unroll
    for (int nb = 0; nb < 2; ++nb) {
        mrow[nb] = (f32x4){-1e30f, -1e30f, -1e30f, -1e30f};
        lrow[nb] = (f32x4){0.f, 0.f, 0.f, 0.f};
    }

    #pragma unroll 1
    for (int kt = 0; kt < 32; ++kt) {
        const int tok0 = kvbase + kt * 64;
        __syncthreads();               // prev PV (P & V reads) done
        #pragma unroll
        for (int it = 0; it < 8; ++it) {          // K tile: 64 x 512B
            int idx = it * 256 + t;
            int m = idx >> 5, c16 = idx & 31;
            u32x4 vv = *(const u32x4*)(Kb + (size_t)(tok0 + m) * CHD + c16 * 8);
            *(u32x4*)(smem + ((m * 512 + c16 * 16) ^ ((m & 7) << 4))) = vv;
        }
        #pragma unroll
        for (int it = 0; it < 8; ++it) {          // V^T tile: 256 x 128B
            int idx = it * 256 + t;
            int d = idx >> 3, m16 = idx & 7;
            u32x4 vv = *(const u32x4*)(Vb + (size_t)d * NTOK + tok0 + m16 * 8);
            *(u32x4*)(smem + 32768 + ((d * 128 + m16 * 16) ^ ((d & 7) << 4))) = vv;
        }
        __syncthreads();

        // S = Q K^T (pre-scaled, log2-domain)
        f32x4 s[2][4];
        #pragma unroll
        for (int nb = 0; nb < 2; ++nb)
            #pragma unroll
            for (int cb = 0; cb < 4; ++cb)
                s[nb][cb] = (f32x4){0.f, 0.f, 0.f, 0.f};
        #pragma unroll
        for (int kk = 0; kk < 8; ++kk) {
            #pragma unroll
            for (int cb = 0; cb < 4; ++cb) {
                int m = cb * 16 + lr;
                bf16x8 kf = *(const bf16x8*)(smem + ((m * 512 + kk * 64 + lg * 16) ^ ((m & 7) << 4)));
                s[0][cb] = mfma16(qf[0][kk], kf, s[0][cb]);
                s[1][cb] = mfma16(qf[1][kk], kf, s[1][cb]);
            }
        }

        // online softmax; C/D rows = lg*4 + r
        f32x4 pb[2][4];
        #pragma unroll
        for (int nb = 0; nb < 2; ++nb) {
            f32x4 resc, psum = (f32x4){0.f, 0.f, 0.f, 0.f};
            #pragma unroll
            for (int r = 0; r < 4; ++r) {
                float mx = fmaxf(fmaxf(s[nb][0][r], s[nb][1][r]), fmaxf(s[nb][2][r], s[nb][3][r]));
                #pragma unroll
                for (int sh = 1; sh < 16; sh <<= 1)
                    mx = fmaxf(mx, __shfl_xor(mx, sh));
                float mn = fmaxf(mrow[nb][r], mx);
                resc[r] = exp2f(mrow[nb][r] - mn);
                mrow[nb][r] = mn;
            }
            #pragma unroll
            for (int cb = 0; cb < 4; ++cb)
                #pragma unroll
                for (int r = 0; r < 4; ++r) {
                    float p = exp2f(s[nb][cb][r] - mrow[nb][r]);
                    pb[nb][cb][r] = p;
                    psum[r] += p;
                }
            #pragma unroll
            for (int r = 0; r < 4; ++r) {
                float ps = psum[r];
                #pragma unroll
                for (int sh = 1; sh < 16; sh <<= 1)
                    ps += __shfl_xor(ps, sh);
                lrow[nb][r] = lrow[nb][r] * resc[r] + ps;
            }
            #pragma unroll
            for (int db = 0; db < 16; ++db)
                #pragma unroll
                for (int r = 0; r < 4; ++r)
                    o[nb][db][r] *= resc[r];
        }

        __syncthreads();   // all waves done reading K region -> P may overlay it

        // P -> bf16, transpose via per-wave LDS scratch (A-fragment layout)
        unsigned char* pbase = smem + wv_ * 4096;
        #pragma unroll
        for (int nb = 0; nb < 2; ++nb)
            #pragma unroll
            for (int cb = 0; cb < 4; ++cb)
                #pragma unroll
                for (int r = 0; r < 4; ++r) {
                    int row = nb * 16 + lg * 4 + r;
                    int col = cb * 16 + lr;
                    *(unsigned short*)(pbase + ((row * 128 + col * 2) ^ ((row & 7) << 4))) =
                        f2bf(pb[nb][cb][r]);
                }

        // O += P V
        #pragma unroll
        for (int ks = 0; ks < 2; ++ks) {
            bf16x8 pa[2];
            #pragma unroll
            for (int nb = 0; nb < 2; ++nb) {
                int row = nb * 16 + lr;
                pa[nb] = *(const bf16x8*)(pbase + ((row * 128 + ks * 64 + lg * 16) ^ ((row & 7) << 4)));
            }
            #pragma unroll
            for (int db = 0; db < 16; ++db) {
                int d = db * 16 + lr;
                bf16x8 vf = *(const bf16x8*)(smem + 32768 + ((d * 128 + ks * 64 + lg * 16) ^ ((d & 7) << 4)));
                o[0][db] = mfma16(pa[0], vf, o[0][db]);
                o[1][db] = mfma16(pa[1], vf, o[1][db]);
            }
        }
    }

    // epilogue: unnormalized O (bf16) + m,l per row
    unsigned short* Ob = Opart + (size_t)(b * 2 + hf) * CHD * NTOK;
    #pragma unroll
    for (int nb = 0; nb < 2; ++nb)
        #pragma unroll
        for (int db = 0; db < 16; ++db) {
            int d = db * 16 + lr;
            int n = n0 + wv_ * 32 + nb * 16 + lg * 4;
            u32x2 pk;
            pk[0] = (unsigned)f2bf(o[nb][db][0]) | ((unsigned)f2bf(o[nb][db][1]) << 16);
            pk[1] = (unsigned)f2bf(o[nb][db][2]) | ((unsigned)f2bf(o[nb][db][3]) << 16);
            *(u32x2*)(Ob + (size_t)d * NTOK + n) = pk;
        }
    if (lr == 0) {
        #pragma unroll
        for (int nb = 0; nb < 2; ++nb)
            #pragma unroll
            for (int r = 0; r < 4; ++r) {
                int n = n0 + wv_ * 32 + nb * 16 + lg * 4 + r;
                Mpart[(size_t)(b * 2 + hf) * NTOK + n] = mrow[nb][r];
                Lpart[(size_t)(b * 2 + hf) * NTOK + n] = lrow[nb][r];
            }
    }
}

// ---------------- kernel 4: merge the two KV-half partials ------------------
__global__ __launch_bounds__(256) void merge_kernel(
    const unsigned short* __restrict__ Opart,
    const float* __restrict__ Mpart, const float* __restrict__ Lpart,
    float* __restrict__ out)
{
    int tid = blockIdx.x * 256 + threadIdx.x;     // 1,048,576 threads, 4 outputs each
    int n = (tid & 1023) * 4;
    int c = (tid >> 10) & 255;
    int b = tid >> 18;
    const size_t p0 = (size_t)(b * 2 + 0) * CHD * NTOK + (size_t)c * NTOK + n;
    const size_t p1 = (size_t)(b * 2 + 1) * CHD * NTOK + (size_t)c * NTOK + n;
    u32x2 o0 = *(const u32x2*)(Opart + p0);
    u32x2 o1 = *(const u32x2*)(Opart + p1);
    f32x4 m0 = *(const f32x4*)(Mpart + (size_t)(b * 2 + 0) * NTOK + n);
    f32x4 m1 = *(const f32x4*)(Mpart + (size_t)(b * 2 + 1) * NTOK + n);
    f32x4 l0 = *(const f32x4*)(Lpart + (size_t)(b * 2 + 0) * NTOK + n);
    f32x4 l1 = *(const f32x4*)(Lpart + (size_t)(b * 2 + 1) * NTOK + n);
    f32x4 res;
    #pragma unroll
    for (int r = 0; r < 4; ++r) {
        float mm = fmaxf(m0[r], m1[r]);
        float s0 = exp2f(m0[r] - mm);
        float s1 = exp2f(m1[r] - mm);
        float denom = l0[r] * s0 + l1[r] * s1;
        float f0 = bf2f((unsigned short)(o0[r >> 1] >> ((r & 1) * 16)));
        float f1 = bf2f((unsigned short)(o1[r >> 1] >> ((r & 1) * 16)));
        res[r] = (f0 * s0 + f1 * s1) / denom;
    }
    *(f32x4*)(out + (size_t)b * CHD * NTOK + (size_t)c * NTOK + n) = res;
}

// ---------------------------------------------------------------------------
extern "C" void kernel_launch(void* const* d_in, const int* in_sizes, int n_in,
                              void* d_out, int out_size, void* d_ws, size_t ws_size,
                              hipStream_t stream) {
    const float* xq = (const float*)d_in[0];
    const float* xk = (const float*)d_in[1];
    const float* xv = (const float*)d_in[2];
    const float* wq = (const float*)d_in[3];
    const float* bq = (const float*)d_in[4];
    const float* wk = (const float*)d_in[5];
    const float* bk = (const float*)d_in[6];
    const float* wv = (const float*)d_in[7];
    const float* bv = (const float*)d_in[8];

    char* ws = (char*)d_ws;
    unsigned short* wbf = (unsigned short*)ws;                           // 393,216 B
    unsigned short* Qp  = (unsigned short*)(ws + 393216);                // 8 MB
    unsigned short* Kp  = (unsigned short*)(ws + 393216 + 8388608);      // 8 MB
    unsigned short* VTp = (unsigned short*)(ws + 393216 + 2 * 8388608);  // 8 MB
    unsigned short* Op  = (unsigned short*)(ws + 393216 + 3 * 8388608);  // 16 MB
    float* Mp = (float*)(ws + 393216 + 3 * 8388608 + 16777216);          // 128 KB
    float* Lp = (float*)(ws + 393216 + 3 * 8388608 + 16777216 + 131072); // 128 KB

    hipLaunchKernelGGL(wconv_kernel, dim3(768), dim3(256), 0, stream, wq, wk, wv, wbf);
    hipLaunchKernelGGL(proj_kernel, dim3(256, 3), dim3(256), 0, stream,
                       xq, xk, xv, bq, bk, bv, wbf, Qp, Kp, VTp);
    hipLaunchKernelGGL(attn_kernel, dim3(256), dim3(256), 0, stream, Qp, Kp, VTp, Op, Mp, Lp);
    hipLaunchKernelGGL(merge_kernel, dim3(4096), dim3(256), 0, stream, Op, Mp, Lp, (float*)d_out);
}